// Round 7
// baseline (179.409 us; speedup 1.0000x reference)
//
#include <hip/hip_runtime.h>

// Problem constants
#define BB   4
#define CC   144
#define HW   4096      // 64*64
#define PTOT 16384     // BB*HW
#define EPSB 1e-5f

typedef __bf16 bf16;
typedef __bf16 bf16x8 __attribute__((ext_vector_type(8)));
typedef float  f32x4  __attribute__((ext_vector_type(4)));
typedef unsigned short U16;
typedef unsigned int   U32;
typedef U16 u16x4 __attribute__((ext_vector_type(4)));
typedef U16 u16x8 __attribute__((ext_vector_type(8)));

#define MFMA __builtin_amdgcn_mfma_f32_16x16x32_bf16

// ---- workspace layout (bytes) ----
#define XN_OFF    0UL         // bf16 [16384][144] channel-last   4,718,592
#define A2_OFF    57147392UL  // bf16 [16384][9][64] (k=rs*64+c2) 18,874,368
#define WINF_OFF  76021760UL  // bf16 frag [4][5][64][8]          20,480
#define W1F_OFF   76042240UL  // bf16 frag [4][18][64][8]         73,728
#define W2F_OFF   76115968UL  // bf16 frag [4][18][64][8]         73,728
#define WOUTF_OFF 76189696UL  // bf16 frag [9][2][64][8]          18,432
#define BNP_OFF   76208128UL  // f32 [672]

// ------------------------------------------------------------------
// K1: L2 normalize over channel dim -> xn channel-last [p][144] bf16
__global__ __launch_bounds__(256) void k_norm(const float* __restrict__ x,
                                              bf16* __restrict__ xn)
{
    __shared__ float red[4][64];
    int bh = blockIdx.x;
    int b = bh >> 6, h = bh & 63;
    int t = threadIdx.x, w = t & 63, cq = t >> 6;
    const float* px = x + ((size_t)b*CC)*HW + h*64 + w;
    float vals[36];
    float s = 0.f;
    #pragma unroll
    for (int i = 0; i < 36; i++) { float v = px[(size_t)(cq*36 + i)*HW]; vals[i] = v; s += v*v; }
    red[cq][w] = s;
    __syncthreads();
    float tot = red[0][w] + red[1][w] + red[2][w] + red[3][w];
    float inv = 1.f / fmaxf(sqrtf(tot), 1e-12f);
    U16* po = (U16*)(xn + ((size_t)(bh*64 + w))*144 + cq*36);
    #pragma unroll
    for (int k = 0; k < 9; k++) {
        u16x4 pk;
        #pragma unroll
        for (int r = 0; r < 4; r++) { bf16 v = (bf16)(vals[k*4+r]*inv); pk[r] = *(U16*)&v; }
        *(u16x4*)(po + k*4) = pk;
    }
}

// ------------------------------------------------------------------
// K2: pack weights into MFMA A-fragment order + fold BN params
__global__ __launch_bounds__(256) void k_pack(
    const float* __restrict__ w_in, const float* __restrict__ w1,
    const float* __restrict__ w2,   const float* __restrict__ w_out,
    const float* g_in, const float* b_in, const float* m_in, const float* v_in,
    const float* g1,   const float* b1,   const float* m1,   const float* v1,
    const float* g2,   const float* b2,   const float* m2,   const float* v2,
    const float* g_out,const float* b_out,const float* m_out,const float* v_out,
    bf16* w_inf, bf16* w1f, bf16* w2f, bf16* w_outf, float* bnp)
{
    int t = blockIdx.x*256 + threadIdx.x;
    if (t < 10240) {                       // w_inf: k = c, padded 144->160
        int e = t, j = e & 7, lane = (e >> 3) & 63, r = e >> 9;
        int ks = r % 5, mt = r / 5;
        int o = mt*16 + (lane & 15);
        int c = ks*32 + ((lane >> 4) << 3) + j;
        w_inf[e] = (c < 144) ? (bf16)w_in[o*144 + c] : (bf16)0.f;
    } else if (t < 47104) {                // w1f: K=576, k = ij*64 + c
        int e = t - 10240, j = e & 7, lane = (e >> 3) & 63, r = e >> 9;
        int ks = r % 18, mt = r / 18;
        int o = mt*16 + (lane & 15);
        int k = ks*32 + ((lane >> 4) << 3) + j;
        int ij = k >> 6, c = k & 63;
        w1f[e] = (bf16)w1[(o*64 + c)*9 + ij];
    } else if (t < 83968) {                // w2f: k = rs*64 + c2 (matches a2 [p][rs][c2])
        int e = t - 47104, j = e & 7, lane = (e >> 3) & 63, r = e >> 9;
        int ks = r % 18, mt = r / 18;
        int o = mt*16 + (lane & 15);
        int k = ks*32 + ((lane >> 4) << 3) + j;
        int rs = k >> 6, c2 = k & 63;
        w2f[e] = (bf16)w2[o*576 + c2*9 + rs];
    } else if (t < 93184) {                // w_outf: M=144 (9 mt), K=64 (2 ks)
        int e = t - 83968, j = e & 7, lane = (e >> 3) & 63, r = e >> 9;
        int ks = r & 1, mt = r >> 1;
        int o = mt*16 + (lane & 15);
        int c = ks*32 + ((lane >> 4) << 3) + j;
        w_outf[e] = (bf16)w_out[o*64 + c];
    } else if (t < 93856) {                // BN fold
        int i = t - 93184;
        const float *g, *bb, *mm, *vv; int c; bool is_t;
        if (i < 128)      { g=g_in; bb=b_in; mm=m_in; vv=v_in; c=i&63;        is_t=i>=64;  }
        else if (i < 256) { g=g1;   bb=b1;   mm=m1;   vv=v1;   c=(i-128)&63;  is_t=i>=192; }
        else if (i < 384) { g=g2;   bb=b2;   mm=m2;   vv=v2;   c=(i-256)&63;  is_t=i>=320; }
        else              { int ii=i-384; g=g_out; bb=b_out; mm=m_out; vv=v_out;
                            c = ii % 144; is_t = ii >= 144; }
        float s = g[c] * rsqrtf(vv[c] + EPSB);
        bnp[i] = is_t ? (bb[c] - mm[c]*s) : s;
    }
}

// ------------------------------------------------------------------
// K3: FUSED stage1+stage2. Block = 16 positions; a1 tile lives in LDS only.
// LDS addr(prow,kp,c) = prow*1600 + kp*64 + (((c>>3) + kp*3 + prow)&7)*8 + (c&7)
// Stage1: waves split 25 kp (4/7/7/7); direct L1-hot xn loads; BN1+ReLU -> LDS.
// Stage2: waves split 9 rs-tiles (3/2/2/2); GEMM M=64,K=576,N=16/tile -> a2.
__global__ __launch_bounds__(256) void k_s12(const bf16* __restrict__ xn,
        const bf16* __restrict__ w_inf, const bf16* __restrict__ w1f,
        const float* __restrict__ bnp, bf16* __restrict__ a2)
{
    __shared__ __align__(16) U16 a1t[16*1600];   // 51200 B -> 3 blocks/CU
    int t = threadIdx.x;
    int wid = t >> 6, lane = t & 63, quad = lane >> 4, col16 = lane & 15;
    int bid = blockIdx.x;
    bid = (bid & 7)*128 + (bid >> 3);            // XCD-contiguous ranges
    int p0 = bid*16;
    int hh = (p0 >> 6) & 63, w0 = p0 & 63;
    int p = p0 + col16;
    int w = w0 + col16;
    const bf16* xrow = xn + (size_t)p*144;

    // ---- stage 1 ----
    bf16x8 af[4][5];
    #pragma unroll
    for (int mt = 0; mt < 4; mt++)
        #pragma unroll
        for (int ks = 0; ks < 5; ks++)
            af[mt][ks] = *(const bf16x8*)(w_inf + ((mt*5 + ks)*64 + lane)*8);
    bf16x8 cfr[5];
    #pragma unroll
    for (int ks = 0; ks < 5; ks++) {
        bf16x8 z = {};
        cfr[ks] = (ks < 4 || quad < 2) ? *(const bf16x8*)(xrow + ks*32 + quad*8) : z;
    }
    f32x4 sv[4], tv[4];
    #pragma unroll
    for (int mt = 0; mt < 4; mt++) {
        sv[mt] = *(const f32x4*)&bnp[mt*16 + quad*4];
        tv[mt] = *(const f32x4*)&bnp[64 + mt*16 + quad*4];
    }

    int kp0 = (wid == 0) ? 0 : (4 + (wid - 1)*7);
    int nkp = (wid == 0) ? 4 : 7;
    for (int ki = 0; ki < nkp; ki++) {
        int kp = kp0 + ki;
        int dh = kp/5 - 2, dw = kp - 5*(kp/5) - 2;
        bool valid = ((unsigned)(hh + dh) < 64u) && ((unsigned)(w + dw) < 64u);
        const bf16* nrow = xrow + (dh*64 + dw)*144;
        f32x4 acc[4] = {};
        #pragma unroll
        for (int ks = 0; ks < 5; ks++) {
            bf16x8 bfr = {};
            if (valid && (ks < 4 || quad < 2)) {
                bf16x8 nv = *(const bf16x8*)(nrow + ks*32 + quad*8);
                #pragma unroll
                for (int j = 0; j < 8; j++)
                    bfr[j] = (bf16)((float)nv[j] * (float)cfr[ks][j]);
            }
            #pragma unroll
            for (int mt = 0; mt < 4; mt++)
                acc[mt] = MFMA(af[mt][ks], bfr, acc[mt], 0, 0, 0);
        }
        #pragma unroll
        for (int mt = 0; mt < 4; mt++) {
            u16x4 pk;
            #pragma unroll
            for (int r = 0; r < 4; r++) {
                bf16 v = (bf16)fmaxf(acc[mt][r]*sv[mt][r] + tv[mt][r], 0.f);
                pk[r] = *(U16*)&v;
            }
            int c = mt*16 + quad*4;
            int dst = col16*1600 + kp*64 + (((c >> 3) + kp*3 + col16) & 7)*8 + (c & 7);
            *(u16x4*)&a1t[dst] = pk;
        }
    }
    __syncthreads();

    // ---- stage 2 ----
    const int LUT5[9] = {0,1,2,5,6,7,10,11,12};
    const int rsbase[4] = {0,3,5,7};
    int rs0 = rsbase[wid];
    int nrs = (wid == 0) ? 3 : 2;
    int lkp[3];
    #pragma unroll
    for (int u = 0; u < 3; u++) lkp[u] = (u < nrs) ? LUT5[rs0 + u] : 0;

    f32x4 acc2[3][4] = {};
    #pragma unroll
    for (int ks = 0; ks < 18; ks++) {
        int ij = ks >> 1, half = ks & 1;
        bf16x8 afr[4];
        #pragma unroll
        for (int mt = 0; mt < 4; mt++)
            afr[mt] = *(const bf16x8*)(w1f + ((mt*18 + ks)*64 + lane)*8);
        #pragma unroll
        for (int u = 0; u < 3; u++) {
            if (u < nrs) {
                int kp = LUT5[ij] + lkp[u];
                int g = half*4 + quad;
                int off = col16*1600 + kp*64 + ((g + kp*3 + col16) & 7)*8;
                bf16x8 bfr = *(const bf16x8*)&a1t[off];
                #pragma unroll
                for (int mt = 0; mt < 4; mt++)
                    acc2[u][mt] = MFMA(afr[mt], bfr, acc2[u][mt], 0, 0, 0);
            }
        }
    }
    // epilogue: BN2 + ReLU -> a2[p][rs][c2]
    #pragma unroll
    for (int u = 0; u < 3; u++) {
        if (u < nrs) {
            U32 ob = (U32)p*576 + (U32)(rs0 + u)*64;
            #pragma unroll
            for (int mt = 0; mt < 4; mt++) {
                int o = mt*16 + quad*4;
                f32x4 s = *(const f32x4*)&bnp[128 + o];
                f32x4 tt = *(const f32x4*)&bnp[192 + o];
                u16x4 pk;
                #pragma unroll
                for (int r = 0; r < 4; r++) {
                    bf16 v = (bf16)fmaxf(acc2[u][mt][r]*s[r] + tt[r], 0.f);
                    pk[r] = *(U16*)&v;
                }
                *(u16x4*)(a2 + ob + o) = pk;
            }
        }
    }
}

// ------------------------------------------------------------------
// K4: stage 3 (64x576, 32 cols/block; a2 chunk staged to LDS swizzled)
//     + BN/ReLU -> swizzled v3 -> stage 4 (144x64) + final BN -> fp32 out.
__global__ __launch_bounds__(256) void k_s34(const bf16* __restrict__ a2,
        const bf16* __restrict__ w2f, const bf16* __restrict__ w_outf,
        const float* __restrict__ bnp, float* __restrict__ out)
{
    __shared__ __align__(16) U16 As[32*576];  // 36864 B
    __shared__ __align__(16) U16 v3[32*64];   // 4096 B
    int t = threadIdx.x, wid = t >> 6, lane = t & 63, quad = lane >> 4, col16 = lane & 15;
    int p0 = blockIdx.x * 32;
    int b = p0 >> 12, hw0 = p0 & 4095;

    const U16* gsrc = (const U16*)(a2 + (size_t)p0*576);
    u16x8 sreg[9];
    #pragma unroll
    for (int it = 0; it < 9; it++) sreg[it] = *(const u16x8*)(gsrc + (it*256 + t)*8);
    #pragma unroll
    for (int it = 0; it < 9; it++) {
        int i = it*256 + t;
        int c = i % 72, pr = i / 72;
        int dst = pr*576 + (c >> 3)*64 + ((((c & 7) + pr) & 7) << 3);
        *(u16x8*)&As[dst] = sreg[it];
    }
    bf16x8 aa[2];
    aa[0] = *(const bf16x8*)(w2f + ((wid*18)*64 + lane)*8);
    __syncthreads();

    f32x4 acc[2] = {};
    #pragma unroll
    for (int ks = 0; ks < 18; ks++) {
        if (ks + 1 < 18)
            aa[(ks+1) & 1] = *(const bf16x8*)(w2f + ((wid*18 + ks + 1)*64 + lane)*8);
        #pragma unroll
        for (int nt = 0; nt < 2; nt++) {
            int p = nt*16 + col16;
            int c = ks*4 + quad;
            int off = p*576 + (c >> 3)*64 + ((((c & 7) + p) & 7) << 3);
            bf16x8 bfr = *(const bf16x8*)&As[off];
            acc[nt] = MFMA(aa[ks & 1], bfr, acc[nt], 0, 0, 0);
        }
    }
    #pragma unroll
    for (int nt = 0; nt < 2; nt++) {
        int colA = nt*16 + col16;
        #pragma unroll
        for (int r = 0; r < 4; r++) {
            int o = wid*16 + quad*4 + r;
            float s = bnp[256 + o], tt = bnp[320 + o];
            bf16 yb = (bf16)fmaxf(acc[nt][r]*s + tt, 0.f);
            v3[colA*64 + (((o >> 3) + colA) & 7)*8 + (o & 7)] = *(U16*)&yb;
        }
    }
    __syncthreads();
    for (int mt = wid; mt < 9; mt += 4) {
        f32x4 accB[2] = {};
        #pragma unroll
        for (int ks = 0; ks < 2; ks++) {
            bf16x8 afr = *(const bf16x8*)(w_outf + ((mt*2 + ks)*64 + lane)*8);
            #pragma unroll
            for (int nt = 0; nt < 2; nt++) {
                int colA = nt*16 + col16;
                int g = ks*4 + quad;
                bf16x8 bfr = *(const bf16x8*)&v3[colA*64 + ((g + colA) & 7)*8];
                accB[nt] = MFMA(afr, bfr, accB[nt], 0, 0, 0);
            }
        }
        #pragma unroll
        for (int nt = 0; nt < 2; nt++) {
            #pragma unroll
            for (int r = 0; r < 4; r++) {
                int oc = mt*16 + quad*4 + r;
                float s = bnp[384 + oc], tt = bnp[528 + oc];
                out[((size_t)(b*144 + oc))*4096 + hw0 + nt*16 + col16] = accB[nt][r]*s + tt;
            }
        }
    }
}

// ------------------------------------------------------------------
extern "C" void kernel_launch(void* const* d_in, const int* in_sizes, int n_in,
                              void* d_out, int out_size, void* d_ws, size_t ws_size,
                              hipStream_t stream)
{
    const float* x     = (const float*)d_in[0];
    const float* w_in  = (const float*)d_in[1];
    const float* g_in  = (const float*)d_in[2];
    const float* b_in  = (const float*)d_in[3];
    const float* m_in  = (const float*)d_in[4];
    const float* v_in  = (const float*)d_in[5];
    const float* w1    = (const float*)d_in[6];
    const float* g1    = (const float*)d_in[7];
    const float* b1    = (const float*)d_in[8];
    const float* m1    = (const float*)d_in[9];
    const float* v1    = (const float*)d_in[10];
    const float* w2    = (const float*)d_in[11];
    const float* g2    = (const float*)d_in[12];
    const float* b2    = (const float*)d_in[13];
    const float* m2    = (const float*)d_in[14];
    const float* v2    = (const float*)d_in[15];
    const float* w_out = (const float*)d_in[16];
    const float* g_out = (const float*)d_in[17];
    const float* b_out = (const float*)d_in[18];
    const float* m_out = (const float*)d_in[19];
    const float* v_out = (const float*)d_in[20];
    float* out = (float*)d_out;

    char* ws = (char*)d_ws;
    bf16*  xn     = (bf16*)(ws + XN_OFF);
    bf16*  a2     = (bf16*)(ws + A2_OFF);
    bf16*  w_inf  = (bf16*)(ws + WINF_OFF);
    bf16*  w1f    = (bf16*)(ws + W1F_OFF);
    bf16*  w2f    = (bf16*)(ws + W2F_OFF);
    bf16*  w_outf = (bf16*)(ws + WOUTF_OFF);
    float* bnp    = (float*)(ws + BNP_OFF);

    hipLaunchKernelGGL(k_norm, dim3(256), dim3(256), 0, stream, x, xn);
    hipLaunchKernelGGL(k_pack, dim3(367), dim3(256), 0, stream,
                       w_in, w1, w2, w_out,
                       g_in, b_in, m_in, v_in, g1, b1, m1, v1,
                       g2, b2, m2, v2, g_out, b_out, m_out, v_out,
                       w_inf, w1f, w2f, w_outf, bnp);
    hipLaunchKernelGGL(k_s12, dim3(1024), dim3(256), 0, stream, xn, w_inf, w1f, bnp, a2);
    hipLaunchKernelGGL(k_s34, dim3(512), dim3(256), 0, stream, a2, w2f, w_outf, bnp, out);
}